// Round 12
// baseline (94.891 us; speedup 1.0000x reference)
//
#include <hip/hip_runtime.h>
#include <hip/hip_bf16.h>
#include <stdint.h>

#define B_ 64
#define N_ 1024
#define D_ 128

typedef __attribute__((ext_vector_type(8))) short bf16x8;
typedef __attribute__((ext_vector_type(4))) float f32x4;

__device__ __forceinline__ unsigned short f2bf(float f) {
    union { float f; uint32_t u; } v; v.f = f;
    uint32_t u = v.u;
    return (unsigned short)((u + 0x7FFFu + ((u >> 16) & 1u)) >> 16);
}

// ---------------------------------------------------------------------------
// Kernel 1: W (f32 [k=128][d=128]) -> bf16 W^T [d][k]; also zeroes the
// attn work counter (replaces hipMemsetAsync).
__global__ __launch_bounds__(256) void wtrans_kernel(
    const float* __restrict__ Wq, const float* __restrict__ Wk,
    const float* __restrict__ Wv, unsigned short* __restrict__ wt,
    int* __restrict__ ctr)
{
    if (blockIdx.x == 0 && threadIdx.x == 0) ctr[0] = 0;
    int p = blockIdx.x >> 4;
    int seg = blockIdx.x & 15;
    const float* W = (p == 0) ? Wq : (p == 1) ? Wk : Wv;
    unsigned short* dst = wt + p * (D_ * D_);
    for (int i = 0; i < 4; ++i) {
        int idx = seg * 1024 + i * 256 + (int)threadIdx.x;
        int k = idx >> 7, d = idx & 127;
        dst[d * D_ + k] = f2bf(W[idx]);
    }
}

// ---------------------------------------------------------------------------
// Kernel 2: QKV projection (unchanged, verified). q,k row-major bf16; v stored
// transposed (V^T [B][D][N]); 1/sqrt(D) folded into q.
__global__ __launch_bounds__(256) void proj_kernel(
    const float* __restrict__ x,
    const unsigned short* __restrict__ wtg,
    const float* __restrict__ bq, const float* __restrict__ bk,
    const float* __restrict__ bv,
    unsigned short* __restrict__ qo, unsigned short* __restrict__ ko,
    unsigned short* __restrict__ vto)
{
    __shared__ alignas(16) unsigned short xs[64 * 136];
    __shared__ alignas(16) unsigned short ws[128 * 136];
    const int tid = threadIdx.x;
    const int row0 = blockIdx.x * 64;

    for (int it = 0; it < 8; ++it) {
        int idx4 = it * 256 + tid;
        int r = idx4 >> 5, c4 = (idx4 & 31) * 4;
        const float4 v = *(const float4*)&x[(size_t)(row0 + r) * D_ + c4];
        unsigned short tmp[4] = { f2bf(v.x), f2bf(v.y), f2bf(v.z), f2bf(v.w) };
        *(uint2*)&xs[r * 136 + c4] = *(uint2*)tmp;
    }

    const int wave = tid >> 6, lane = tid & 63;
    const int lr = lane & 15, lg = lane >> 4;
    const f32x4 zero4 = {0.f, 0.f, 0.f, 0.f};

    for (int p = 0; p < 3; ++p) {
        __syncthreads();
        const unsigned short* wsrc = wtg + p * (D_ * D_);
        for (int it = 0; it < 8; ++it) {
            int idx8 = it * 256 + tid;
            int r = idx8 >> 4, c8 = (idx8 & 15) * 8;
            *(bf16x8*)&ws[r * 136 + c8] = *(const bf16x8*)&wsrc[idx8 * 8];
        }
        __syncthreads();

        bf16x8 a[4];
        for (int kk = 0; kk < 4; ++kk)
            a[kk] = *(const bf16x8*)&xs[(wave * 16 + lr) * 136 + kk * 32 + lg * 8];
        f32x4 acc[8];
        for (int nt = 0; nt < 8; ++nt) acc[nt] = zero4;
        for (int kk = 0; kk < 4; ++kk)
            for (int nt = 0; nt < 8; ++nt) {
                bf16x8 bfr = *(const bf16x8*)&ws[(nt * 16 + lr) * 136 + kk * 32 + lg * 8];
                acc[nt] = __builtin_amdgcn_mfma_f32_16x16x32_bf16(a[kk], bfr, acc[nt], 0, 0, 0);
            }

        if (p < 2) {
            const float* bias = (p == 0) ? bq : bk;
            unsigned short* outp = (p == 0) ? qo : ko;
            const float sc = (p == 0) ? 0.08838834764831845f : 1.0f;
            for (int nt = 0; nt < 8; ++nt) {
                int d = nt * 16 + lr;
                float bb = bias[d];
                for (int r = 0; r < 4; ++r) {
                    int grow = row0 + wave * 16 + lg * 4 + r;
                    outp[(size_t)grow * D_ + d] = f2bf((acc[nt][r] + bb) * sc);
                }
            }
        } else {
            __syncthreads();
            for (int nt = 0; nt < 8; ++nt) {
                int d = nt * 16 + lr;
                float bb = bv[d];
                for (int r = 0; r < 4; ++r)
                    ws[d * 72 + wave * 16 + lg * 4 + r] = f2bf(acc[nt][r] + bb);
            }
            __syncthreads();
            const int b = row0 >> 10, n0 = row0 & 1023;
            unsigned short* dst = vto + ((size_t)b * D_) * N_ + n0;
            for (int it = 0; it < 4; ++it) {
                int idx = it * 256 + tid;
                int d = idx >> 3, c8 = (idx & 7) * 8;
                *(bf16x8*)&dst[(size_t)d * N_ + c8] = *(const bf16x8*)&ws[d * 72 + c8];
            }
        }
    }
}

// ---------------------------------------------------------------------------
// Kernel 3: persistent flash attention. r11 structure, but V comes DIRECTLY
// from global/L2 into a batched, pinned register array (vf[16], issued before
// QK^T, consumed ~900cy later in PV) -- removes the V LDS buffers, staging
// writes and 4x-redundant V LDS reads (~45% of the LDS-pipe bytes that bound
// r9-r11). K stays LDS double-buffered. Requires the (512,1) 256-VGPR budget
// (r8's identical attempt failed only because of the 128-VGPR clamp).
__global__ __launch_bounds__(512, 1) void attn_kernel(
    const unsigned short* __restrict__ qg, const unsigned short* __restrict__ kg,
    const unsigned short* __restrict__ vtg, const int* __restrict__ valid_lens,
    float* __restrict__ out, int* __restrict__ ctr)
{
    // smem (ushorts): ks[grp][buf][64*136] -> 34816; cmb aliases it (dead)
    __shared__ alignas(16) unsigned short smem[34816];
    __shared__ int slot;

    const int tid = threadIdx.x;
    const int wave = tid >> 6, lane = tid & 63;
    const int lr = lane & 15, lg = lane >> 4;
    const int grp = tid >> 8;            // 0: waves 0-3, 1: waves 4-7
    const int wg = wave & 3;             // q-row group within the item
    const int t256 = tid & 255;
    const int k_r = t256 >> 4, k_c = (t256 & 15) * 8;
    unsigned short* const ks_base = smem + grp * 17408;          // 2 bufs of 8704
    float* const cmbO = (float*)smem;                 // [128][130] (dead alias)
    float* const cmbL = ((float*)smem) + 16640;       // [128]
    const f32x4 zero4 = {0.f, 0.f, 0.f, 0.f};
    const bool hbit = (lg >> 1) != 0;
    const bool mbit = (lg & 1) != 0;

    int item = blockIdx.x;
    while (item < 512) {
        const int qt = 7 - (item >> 6);           // heavy (high-qt) items first
        const int b  = item & 63;
        const int L  = valid_lens[b];
        const int q0 = qt * 128;
        float* outb = out + ((size_t)b * N_ + q0) * D_;

        if (q0 >= L) {
            #pragma unroll
            for (int it = 0; it < 8; ++it) {
                int idx4 = it * 512 + tid;
                int r = idx4 >> 5, c4 = (idx4 & 31) * 4;
                float4 z; z.x = z.y = z.z = z.w = 0.f;
                *(float4*)&outb[(size_t)r * D_ + c4] = z;
            }
        } else {
            const int ntiles = (L + 63) >> 6;
            const int H = (ntiles + 1) >> 1;
            const int myStart = grp ? H : 0;
            const int myCnt = grp ? (ntiles - H) : H;
            const unsigned short* kgb = kg + (size_t)b * N_ * D_;
            const unsigned short* vtb = vtg + (size_t)b * D_ * N_;

            // Q fragments (B-operand in swapped QK^T: lane lr = q-row)
            bf16x8 aq[2][4];
            #pragma unroll
            for (int rt = 0; rt < 2; ++rt) {
                const unsigned short* qrow =
                    qg + ((size_t)b * N_ + q0 + wg * 32 + rt * 16 + lr) * D_;
                #pragma unroll
                for (int kk = 0; kk < 4; ++kk)
                    aq[rt][kk] = *(const bf16x8*)&qrow[kk * 32 + lg * 8];
            }

            f32x4 oacc[2][8];
            #pragma unroll
            for (int rt = 0; rt < 2; ++rt)
                #pragma unroll
                for (int i = 0; i < 8; ++i) oacc[rt][i] = zero4;
            float lsum[2] = {0.f, 0.f};

            bf16x8 kreg[4];

            // prologue: stage my stream's first K tile into buf0
            if (myCnt > 0) {
                const int kv0 = myStart * 64;
                #pragma unroll
                for (int it = 0; it < 4; ++it)
                    kreg[it] = *(const bf16x8*)&kgb[(size_t)(kv0 + it * 16 + k_r) * D_ + k_c];
                #pragma unroll
                for (int it = 0; it < 4; ++it)
                    *(bf16x8*)&ks_base[(it * 16 + k_r) * 136 + k_c] = kreg[it];
            }
            __syncthreads();

            for (int r = 0; r < H; ++r) {
                const bool valid = (r < myCnt);
                const int kv0 = (myStart + r) * 64;
                const int ko_cur = (r & 1) ? 8704 : 0;     // branch-free buf select
                unsigned short* const ks_my = ks_base + ko_cur;

                // V fragments for THIS tile: batch-issue, consume after softmax
                bf16x8 vf[16];
                if (valid) {
                    #pragma unroll
                    for (int nt = 0; nt < 8; ++nt)
                        #pragma unroll
                        for (int kk = 0; kk < 2; ++kk)
                            vf[nt * 2 + kk] = *(const bf16x8*)
                                &vtb[(size_t)(nt * 16 + lr) * N_ + kv0 + kk * 32 + lg * 8];
                    __builtin_amdgcn_sched_barrier(0);  // pin the batch
                }
                // K staging loads for NEXT tile
                if (r + 1 < myCnt) {
                    const int kvn = kv0 + 64;
                    #pragma unroll
                    for (int it = 0; it < 4; ++it)
                        kreg[it] = *(const bf16x8*)&kgb[(size_t)(kvn + it * 16 + k_r) * D_ + k_c];
                    __builtin_amdgcn_sched_barrier(0);
                }

                if (valid) {
                    // S^T = K Q^T (A=K-frag, B=Q-frag). col=lr=q-row, row=kv.
                    f32x4 s[2][4];
                    __builtin_amdgcn_s_setprio(1);
                    #pragma unroll
                    for (int nt = 0; nt < 4; ++nt) {
                        s[0][nt] = zero4; s[1][nt] = zero4;
                        #pragma unroll
                        for (int kk = 0; kk < 4; ++kk) {
                            bf16x8 bk_ = *(const bf16x8*)&ks_my[(nt * 16 + lr) * 136 + kk * 32 + lg * 8];
                            s[0][nt] = __builtin_amdgcn_mfma_f32_16x16x32_bf16(bk_, aq[0][kk], s[0][nt], 0, 0, 0);
                            s[1][nt] = __builtin_amdgcn_mfma_f32_16x16x32_bf16(bk_, aq[1][kk], s[1][nt], 0, 0, 0);
                        }
                    }
                    __builtin_amdgcn_s_setprio(0);

                    // p = exp(s) (no max), mask kv>=L; pack into u32 pairs
                    uint32_t pwv[2][8];
                    #pragma unroll
                    for (int nt = 0; nt < 4; ++nt) {
                        const int kvb = kv0 + nt * 16 + lg * 4;
                        #pragma unroll
                        for (int rt = 0; rt < 2; ++rt) {
                            float e0 = (kvb + 0 < L) ? __expf(s[rt][nt][0]) : 0.f;
                            float e1 = (kvb + 1 < L) ? __expf(s[rt][nt][1]) : 0.f;
                            float e2 = (kvb + 2 < L) ? __expf(s[rt][nt][2]) : 0.f;
                            float e3 = (kvb + 3 < L) ? __expf(s[rt][nt][3]) : 0.f;
                            lsum[rt] += (e0 + e1) + (e2 + e3);
                            pwv[rt][nt * 2 + 0] = (uint32_t)f2bf(e0) | ((uint32_t)f2bf(e1) << 16);
                            pwv[rt][nt * 2 + 1] = (uint32_t)f2bf(e2) | ((uint32_t)f2bf(e3) << 16);
                        }
                    }

                    // butterfly P-exchange among lanes {lr+16*lg} -> A-frags
                    #pragma unroll
                    for (int rt = 0; rt < 2; ++rt) {
                        uint32_t sh[4], so[4];
                        #pragma unroll
                        for (int i = 0; i < 4; ++i) {
                            int i0 = (i >> 1) * 4 + (i & 1);  // set0 word
                            sh[i] = hbit ? pwv[rt][i0 + 2] : pwv[rt][i0];
                            so[i] = hbit ? pwv[rt][i0] : pwv[rt][i0 + 2];
                        }
                        uint32_t rv[4];
                        #pragma unroll
                        for (int i = 0; i < 4; ++i)
                            rv[i] = __shfl_xor((int)so[i], 32);
                        const bool c2 = (hbit != mbit);
                        uint32_t s2[4], kp[4];
                        #pragma unroll
                        for (int i = 0; i < 4; ++i) {
                            s2[i] = c2 ? sh[i] : rv[i];
                            kp[i] = c2 ? rv[i] : sh[i];
                        }
                        uint32_t r2v[4];
                        #pragma unroll
                        for (int i = 0; i < 4; ++i)
                            r2v[i] = __shfl_xor((int)s2[i], 16);
                        uint32_t apw[2][4];
                        #pragma unroll
                        for (int kk = 0; kk < 2; ++kk)
                            #pragma unroll
                            for (int c = 0; c < 2; ++c) {
                                uint32_t kw = kp[kk * 2 + c], rw = r2v[kk * 2 + c];
                                apw[kk][c]     = mbit ? rw : kw;
                                apw[kk][2 + c] = mbit ? kw : rw;
                            }
                        // O += P V (V from registers)
                        __builtin_amdgcn_s_setprio(1);
                        #pragma unroll
                        for (int kk = 0; kk < 2; ++kk) {
                            bf16x8 ap = *(bf16x8*)&apw[kk][0];
                            #pragma unroll
                            for (int nt = 0; nt < 8; ++nt)
                                oacc[rt][nt] = __builtin_amdgcn_mfma_f32_16x16x32_bf16(ap, vf[nt * 2 + kk], oacc[rt][nt], 0, 0, 0);
                        }
                        __builtin_amdgcn_s_setprio(0);
                    }
                }

                // write next K tile into the idle buffer
                if (r + 1 < myCnt) {
                    unsigned short* const ks_nx = ks_base + (ko_cur ^ 8704);
                    #pragma unroll
                    for (int it = 0; it < 4; ++it)
                        *(bf16x8*)&ks_nx[(it * 16 + k_r) * 136 + k_c] = kreg[it];
                }
                __syncthreads();
            }

            // reduce lane-local denominators across the 4 lg-copies of each q-row
            #pragma unroll
            for (int rt = 0; rt < 2; ++rt) {
                float l = lsum[rt];
                l += __shfl_xor(l, 16);
                l += __shfl_xor(l, 32);
                lsum[rt] = l;
            }

            // combine: group1 publishes partials into dead LDS
            if (grp == 1) {
                #pragma unroll
                for (int rt = 0; rt < 2; ++rt) {
                    if (lg == 0) cmbL[wg * 32 + rt * 16 + lr] = lsum[rt];
                    #pragma unroll
                    for (int r2 = 0; r2 < 4; ++r2) {
                        const int row = wg * 32 + rt * 16 + lg * 4 + r2;
                        #pragma unroll
                        for (int nt = 0; nt < 8; ++nt)
                            cmbO[row * 130 + nt * 16 + lr] = oacc[rt][nt][r2];
                    }
                }
            }
            __syncthreads();
            if (grp == 0) {
                #pragma unroll
                for (int rt = 0; rt < 2; ++rt) {
                    const int qrow = q0 + wg * 32 + rt * 16 + lr;
                    float tot = lsum[rt] + cmbL[wg * 32 + rt * 16 + lr];
                    float invq = (qrow < L) ? 1.0f / tot : 0.0f;
                    #pragma unroll
                    for (int r2 = 0; r2 < 4; ++r2) {
                        const float invr = __shfl(invq, lg * 4 + r2);
                        const int row = wg * 32 + rt * 16 + lg * 4 + r2;
                        #pragma unroll
                        for (int nt = 0; nt < 8; ++nt) {
                            const int col = nt * 16 + lr;
                            outb[(size_t)row * D_ + col] =
                                (oacc[rt][nt][r2] + cmbO[row * 130 + col]) * invr;
                        }
                    }
                }
            }
            __syncthreads();   // cmb area becomes K staging for next item
        }

        // fetch next item (uniform across block)
        if (tid == 0) slot = 256 + atomicAdd(ctr, 1);
        __syncthreads();
        item = slot;
        __syncthreads();
    }
}

// ---------------------------------------------------------------------------
extern "C" void kernel_launch(void* const* d_in, const int* in_sizes, int n_in,
                              void* d_out, int out_size, void* d_ws, size_t ws_size,
                              hipStream_t stream) {
    const float* x    = (const float*)d_in[0];
    const int*   vlen = (const int*)d_in[1];
    const float* Wq   = (const float*)d_in[2];
    const float* bq   = (const float*)d_in[3];
    const float* Wk   = (const float*)d_in[4];
    const float* bk   = (const float*)d_in[5];
    const float* Wv   = (const float*)d_in[6];
    const float* bv   = (const float*)d_in[7];
    float* out = (float*)d_out;

    // ws layout: [W^T bf16 x3 | q bf16 | k bf16 | v^T bf16 | atomic ctr]
    unsigned short* wt  = (unsigned short*)d_ws;                  // 3*128*128
    unsigned short* qws = (unsigned short*)((char*)d_ws + 98304);
    unsigned short* kws = qws + (size_t)B_ * N_ * D_;
    unsigned short* vtws = kws + (size_t)B_ * N_ * D_;
    int* ctr = (int*)((char*)d_ws + 98304 + 3 * (size_t)B_ * N_ * D_ * 2);

    wtrans_kernel<<<48, 256, 0, stream>>>(Wq, Wk, Wv, wt, ctr);
    proj_kernel<<<(B_ * N_) / 64, 256, 0, stream>>>(x, wt, bq, bk, bv, qws, kws, vtws);
    attn_kernel<<<256, 512, 0, stream>>>(qws, kws, vtws, vlen, out, ctr);
}

// Round 13
// 67.120 us; speedup vs baseline: 1.4138x; 1.4138x over previous
//
#include <hip/hip_runtime.h>
#include <hip/hip_bf16.h>
#include <stdint.h>

#define B_ 64
#define N_ 1024
#define D_ 128

typedef __attribute__((ext_vector_type(8))) short bf16x8;
typedef __attribute__((ext_vector_type(4))) float f32x4;

__device__ __forceinline__ unsigned short f2bf(float f) {
    union { float f; uint32_t u; } v; v.f = f;
    uint32_t u = v.u;
    return (unsigned short)((u + 0x7FFFu + ((u >> 16) & 1u)) >> 16);
}

// ---------------------------------------------------------------------------
// Kernel 1: W (f32 [k=128][d=128]) -> bf16 W^T [d][k]; also zeroes the
// attn work counter (replaces hipMemsetAsync).
__global__ __launch_bounds__(256) void wtrans_kernel(
    const float* __restrict__ Wq, const float* __restrict__ Wk,
    const float* __restrict__ Wv, unsigned short* __restrict__ wt,
    int* __restrict__ ctr)
{
    if (blockIdx.x == 0 && threadIdx.x == 0) ctr[0] = 0;
    int p = blockIdx.x >> 4;
    int seg = blockIdx.x & 15;
    const float* W = (p == 0) ? Wq : (p == 1) ? Wk : Wv;
    unsigned short* dst = wt + p * (D_ * D_);
    for (int i = 0; i < 4; ++i) {
        int idx = seg * 1024 + i * 256 + (int)threadIdx.x;
        int k = idx >> 7, d = idx & 127;
        dst[d * D_ + k] = f2bf(W[idx]);
    }
}

// ---------------------------------------------------------------------------
// Kernel 2: QKV projection. q scaled by (1/sqrt(128))*log2(e) so attention's
// softmax uses native v_exp_f32 (exp2) with no multiply. k row-major bf16;
// v stored transposed (V^T [B][D][N]).
__global__ __launch_bounds__(256) void proj_kernel(
    const float* __restrict__ x,
    const unsigned short* __restrict__ wtg,
    const float* __restrict__ bq, const float* __restrict__ bk,
    const float* __restrict__ bv,
    unsigned short* __restrict__ qo, unsigned short* __restrict__ ko,
    unsigned short* __restrict__ vto)
{
    __shared__ alignas(16) unsigned short xs[64 * 136];
    __shared__ alignas(16) unsigned short ws[128 * 136];
    const int tid = threadIdx.x;
    const int row0 = blockIdx.x * 64;

    for (int it = 0; it < 8; ++it) {
        int idx4 = it * 256 + tid;
        int r = idx4 >> 5, c4 = (idx4 & 31) * 4;
        const float4 v = *(const float4*)&x[(size_t)(row0 + r) * D_ + c4];
        unsigned short tmp[4] = { f2bf(v.x), f2bf(v.y), f2bf(v.z), f2bf(v.w) };
        *(uint2*)&xs[r * 136 + c4] = *(uint2*)tmp;
    }

    const int wave = tid >> 6, lane = tid & 63;
    const int lr = lane & 15, lg = lane >> 4;
    const f32x4 zero4 = {0.f, 0.f, 0.f, 0.f};

    for (int p = 0; p < 3; ++p) {
        __syncthreads();
        const unsigned short* wsrc = wtg + p * (D_ * D_);
        for (int it = 0; it < 8; ++it) {
            int idx8 = it * 256 + tid;
            int r = idx8 >> 4, c8 = (idx8 & 15) * 8;
            *(bf16x8*)&ws[r * 136 + c8] = *(const bf16x8*)&wsrc[idx8 * 8];
        }
        __syncthreads();

        bf16x8 a[4];
        for (int kk = 0; kk < 4; ++kk)
            a[kk] = *(const bf16x8*)&xs[(wave * 16 + lr) * 136 + kk * 32 + lg * 8];
        f32x4 acc[8];
        for (int nt = 0; nt < 8; ++nt) acc[nt] = zero4;
        for (int kk = 0; kk < 4; ++kk)
            for (int nt = 0; nt < 8; ++nt) {
                bf16x8 bfr = *(const bf16x8*)&ws[(nt * 16 + lr) * 136 + kk * 32 + lg * 8];
                acc[nt] = __builtin_amdgcn_mfma_f32_16x16x32_bf16(a[kk], bfr, acc[nt], 0, 0, 0);
            }

        if (p < 2) {
            const float* bias = (p == 0) ? bq : bk;
            unsigned short* outp = (p == 0) ? qo : ko;
            // q: 1/sqrt(128) * log2(e) folded (exp2-native softmax)
            const float sc = (p == 0) ? 0.12751741388f : 1.0f;
            for (int nt = 0; nt < 8; ++nt) {
                int d = nt * 16 + lr;
                float bb = bias[d];
                for (int r = 0; r < 4; ++r) {
                    int grow = row0 + wave * 16 + lg * 4 + r;
                    outp[(size_t)grow * D_ + d] = f2bf((acc[nt][r] + bb) * sc);
                }
            }
        } else {
            __syncthreads();
            for (int nt = 0; nt < 8; ++nt) {
                int d = nt * 16 + lr;
                float bb = bv[d];
                for (int r = 0; r < 4; ++r)
                    ws[d * 72 + wave * 16 + lg * 4 + r] = f2bf(acc[nt][r] + bb);
            }
            __syncthreads();
            const int b = row0 >> 10, n0 = row0 & 1023;
            unsigned short* dst = vto + ((size_t)b * D_) * N_ + n0;
            for (int it = 0; it < 4; ++it) {
                int idx = it * 256 + tid;
                int d = idx >> 3, c8 = (idx & 7) * 8;
                *(bf16x8*)&dst[(size_t)d * N_ + c8] = *(const bf16x8*)&ws[d * 72 + c8];
            }
        }
    }
}

// ---------------------------------------------------------------------------
// Kernel 3: persistent flash attention (r11 structure; softmax VALU chain cut
// ~2.5x). exp2-native (scale folded at projection), column masks hoisted to a
// group-uniform branch (full tiles skip 128 compare/select ops), bf16 packing
// via single-instruction v_cvt_pk_bf16_f32. Layouts identical to r11.
__global__ __launch_bounds__(512, 1) void attn_kernel(
    const unsigned short* __restrict__ qg, const unsigned short* __restrict__ kg,
    const unsigned short* __restrict__ vtg, const int* __restrict__ valid_lens,
    float* __restrict__ out, int* __restrict__ ctr)
{
    // smem (ushorts): ks[grp][buf][64*136] | vt[grp][buf][128*72]
    __shared__ alignas(16) unsigned short smem[71680];
    __shared__ int slot;

    const int tid = threadIdx.x;
    const int wave = tid >> 6, lane = tid & 63;
    const int lr = lane & 15, lg = lane >> 4;
    const int grp = tid >> 8;            // 0: waves 0-3, 1: waves 4-7
    const int wg = wave & 3;             // q-row group within the item
    const int t256 = tid & 255;
    const int k_r = t256 >> 4, k_c = (t256 & 15) * 8;
    const int v_d = t256 >> 3, v_c = (t256 & 7) * 8;
    unsigned short* const ks_base = smem + grp * 17408;          // 2 bufs of 8704
    unsigned short* const vt_base = smem + 34816 + grp * 18432;  // 2 bufs of 9216
    float* const cmbO = (float*)smem;                 // [128][130] (dead alias)
    float* const cmbL = ((float*)smem) + 16640;       // [128]
    const f32x4 zero4 = {0.f, 0.f, 0.f, 0.f};
    const bool hbit = (lg >> 1) != 0;
    const bool mbit = (lg & 1) != 0;

    int item = blockIdx.x;
    while (item < 512) {
        const int qt = 7 - (item >> 6);           // heavy (high-qt) items first
        const int b  = item & 63;
        const int L  = valid_lens[b];
        const int q0 = qt * 128;
        float* outb = out + ((size_t)b * N_ + q0) * D_;

        if (q0 >= L) {
            #pragma unroll
            for (int it = 0; it < 8; ++it) {
                int idx4 = it * 512 + tid;
                int r = idx4 >> 5, c4 = (idx4 & 31) * 4;
                float4 z; z.x = z.y = z.z = z.w = 0.f;
                *(float4*)&outb[(size_t)r * D_ + c4] = z;
            }
        } else {
            const int ntiles = (L + 63) >> 6;
            const int H = (ntiles + 1) >> 1;
            const int myStart = grp ? H : 0;
            const int myCnt = grp ? (ntiles - H) : H;
            const unsigned short* kgb = kg + (size_t)b * N_ * D_;
            const unsigned short* vtb = vtg + (size_t)b * D_ * N_;

            // Q fragments (B-operand in swapped QK^T: lane lr = q-row)
            bf16x8 aq[2][4];
            #pragma unroll
            for (int rt = 0; rt < 2; ++rt) {
                const unsigned short* qrow =
                    qg + ((size_t)b * N_ + q0 + wg * 32 + rt * 16 + lr) * D_;
                #pragma unroll
                for (int kk = 0; kk < 4; ++kk)
                    aq[rt][kk] = *(const bf16x8*)&qrow[kk * 32 + lg * 8];
            }

            f32x4 oacc[2][8];
            #pragma unroll
            for (int rt = 0; rt < 2; ++rt)
                #pragma unroll
                for (int i = 0; i < 8; ++i) oacc[rt][i] = zero4;
            float lsum[2] = {0.f, 0.f};

            bf16x8 kreg[4], vreg[4];

            // prologue: stage my stream's first tile into buf0
            if (myCnt > 0) {
                const int kv0 = myStart * 64;
                #pragma unroll
                for (int it = 0; it < 4; ++it)
                    kreg[it] = *(const bf16x8*)&kgb[(size_t)(kv0 + it * 16 + k_r) * D_ + k_c];
                #pragma unroll
                for (int it = 0; it < 4; ++it)
                    vreg[it] = *(const bf16x8*)&vtb[(size_t)(it * 32 + v_d) * N_ + kv0 + v_c];
                #pragma unroll
                for (int it = 0; it < 4; ++it)
                    *(bf16x8*)&ks_base[(it * 16 + k_r) * 136 + k_c] = kreg[it];
                #pragma unroll
                for (int it = 0; it < 4; ++it)
                    *(bf16x8*)&vt_base[(it * 32 + v_d) * 72 + v_c] = vreg[it];
            }
            __syncthreads();

            for (int r = 0; r < H; ++r) {
                const bool valid = (r < myCnt);
                const int kv0 = (myStart + r) * 64;
                const int ko_cur = (r & 1) ? 8704 : 0;     // branch-free buf select
                const int vo_cur = (r & 1) ? 9216 : 0;
                unsigned short* const ks_my = ks_base + ko_cur;
                unsigned short* const vt_my = vt_base + vo_cur;

                if (r + 1 < myCnt) {   // issue next-tile loads before compute
                    const int kvn = kv0 + 64;
                    #pragma unroll
                    for (int it = 0; it < 4; ++it)
                        kreg[it] = *(const bf16x8*)&kgb[(size_t)(kvn + it * 16 + k_r) * D_ + k_c];
                    #pragma unroll
                    for (int it = 0; it < 4; ++it)
                        vreg[it] = *(const bf16x8*)&vtb[(size_t)(it * 32 + v_d) * N_ + kvn + v_c];
                    __builtin_amdgcn_sched_barrier(0);
                }

                if (valid) {
                    // S^T = K Q^T (A=K-frag, B=Q-frag). col=lr=q-row, row=kv.
                    f32x4 s[2][4];
                    __builtin_amdgcn_s_setprio(1);
                    #pragma unroll
                    for (int nt = 0; nt < 4; ++nt) {
                        s[0][nt] = zero4; s[1][nt] = zero4;
                        #pragma unroll
                        for (int kk = 0; kk < 4; ++kk) {
                            bf16x8 bk_ = *(const bf16x8*)&ks_my[(nt * 16 + lr) * 136 + kk * 32 + lg * 8];
                            s[0][nt] = __builtin_amdgcn_mfma_f32_16x16x32_bf16(bk_, aq[0][kk], s[0][nt], 0, 0, 0);
                            s[1][nt] = __builtin_amdgcn_mfma_f32_16x16x32_bf16(bk_, aq[1][kk], s[1][nt], 0, 0, 0);
                        }
                    }
                    __builtin_amdgcn_s_setprio(0);

                    // p = exp2(s) (scale+log2e folded upstream; no max needed).
                    // Full tiles (group-uniform) skip all column-mask ops.
                    uint32_t pwv[2][8];
                    if (kv0 + 64 <= L) {
                        #pragma unroll
                        for (int nt = 0; nt < 4; ++nt)
                            #pragma unroll
                            for (int rt = 0; rt < 2; ++rt) {
                                float e0 = __builtin_amdgcn_exp2f(s[rt][nt][0]);
                                float e1 = __builtin_amdgcn_exp2f(s[rt][nt][1]);
                                float e2 = __builtin_amdgcn_exp2f(s[rt][nt][2]);
                                float e3 = __builtin_amdgcn_exp2f(s[rt][nt][3]);
                                lsum[rt] += (e0 + e1) + (e2 + e3);
                                uint32_t w0, w1;
                                asm("v_cvt_pk_bf16_f32 %0, %1, %2" : "=v"(w0) : "v"(e0), "v"(e1));
                                asm("v_cvt_pk_bf16_f32 %0, %1, %2" : "=v"(w1) : "v"(e2), "v"(e3));
                                pwv[rt][nt * 2 + 0] = w0;
                                pwv[rt][nt * 2 + 1] = w1;
                            }
                    } else {
                        #pragma unroll
                        for (int nt = 0; nt < 4; ++nt) {
                            const int kvb = kv0 + nt * 16 + lg * 4;
                            #pragma unroll
                            for (int rt = 0; rt < 2; ++rt) {
                                float e0 = (kvb + 0 < L) ? __builtin_amdgcn_exp2f(s[rt][nt][0]) : 0.f;
                                float e1 = (kvb + 1 < L) ? __builtin_amdgcn_exp2f(s[rt][nt][1]) : 0.f;
                                float e2 = (kvb + 2 < L) ? __builtin_amdgcn_exp2f(s[rt][nt][2]) : 0.f;
                                float e3 = (kvb + 3 < L) ? __builtin_amdgcn_exp2f(s[rt][nt][3]) : 0.f;
                                lsum[rt] += (e0 + e1) + (e2 + e3);
                                uint32_t w0, w1;
                                asm("v_cvt_pk_bf16_f32 %0, %1, %2" : "=v"(w0) : "v"(e0), "v"(e1));
                                asm("v_cvt_pk_bf16_f32 %0, %1, %2" : "=v"(w1) : "v"(e2), "v"(e3));
                                pwv[rt][nt * 2 + 0] = w0;
                                pwv[rt][nt * 2 + 1] = w1;
                            }
                        }
                    }

                    // butterfly P-exchange among lanes {lr+16*lg} -> A-frags
                    #pragma unroll
                    for (int rt = 0; rt < 2; ++rt) {
                        uint32_t sh[4], so[4];
                        #pragma unroll
                        for (int i = 0; i < 4; ++i) {
                            int i0 = (i >> 1) * 4 + (i & 1);  // set0 word
                            sh[i] = hbit ? pwv[rt][i0 + 2] : pwv[rt][i0];
                            so[i] = hbit ? pwv[rt][i0] : pwv[rt][i0 + 2];
                        }
                        uint32_t rv[4];
                        #pragma unroll
                        for (int i = 0; i < 4; ++i)
                            rv[i] = __shfl_xor((int)so[i], 32);
                        const bool c2 = (hbit != mbit);
                        uint32_t s2[4], kp[4];
                        #pragma unroll
                        for (int i = 0; i < 4; ++i) {
                            s2[i] = c2 ? sh[i] : rv[i];
                            kp[i] = c2 ? rv[i] : sh[i];
                        }
                        uint32_t r2v[4];
                        #pragma unroll
                        for (int i = 0; i < 4; ++i)
                            r2v[i] = __shfl_xor((int)s2[i], 16);
                        uint32_t apw[2][4];
                        #pragma unroll
                        for (int kk = 0; kk < 2; ++kk)
                            #pragma unroll
                            for (int c = 0; c < 2; ++c) {
                                uint32_t kw = kp[kk * 2 + c], rw = r2v[kk * 2 + c];
                                apw[kk][c]     = mbit ? rw : kw;
                                apw[kk][2 + c] = mbit ? kw : rw;
                            }
                        // O += P V (V from LDS)
                        __builtin_amdgcn_s_setprio(1);
                        #pragma unroll
                        for (int kk = 0; kk < 2; ++kk) {
                            bf16x8 ap = *(bf16x8*)&apw[kk][0];
                            #pragma unroll
                            for (int nt = 0; nt < 8; ++nt) {
                                bf16x8 bv_ = *(const bf16x8*)&vt_my[(nt * 16 + lr) * 72 + kk * 32 + lg * 8];
                                oacc[rt][nt] = __builtin_amdgcn_mfma_f32_16x16x32_bf16(ap, bv_, oacc[rt][nt], 0, 0, 0);
                            }
                        }
                        __builtin_amdgcn_s_setprio(0);
                    }
                }

                // write next tile into the idle buffer (its readers finished
                // last round, sealed by that round's barrier)
                if (r + 1 < myCnt) {
                    unsigned short* const ks_nx = ks_base + (ko_cur ^ 8704);
                    unsigned short* const vt_nx = vt_base + (vo_cur ^ 9216);
                    #pragma unroll
                    for (int it = 0; it < 4; ++it)
                        *(bf16x8*)&ks_nx[(it * 16 + k_r) * 136 + k_c] = kreg[it];
                    #pragma unroll
                    for (int it = 0; it < 4; ++it)
                        *(bf16x8*)&vt_nx[(it * 32 + v_d) * 72 + v_c] = vreg[it];
                }
                __syncthreads();
            }

            // reduce lane-local denominators across the 4 lg-copies of each q-row
            #pragma unroll
            for (int rt = 0; rt < 2; ++rt) {
                float l = lsum[rt];
                l += __shfl_xor(l, 16);
                l += __shfl_xor(l, 32);
                lsum[rt] = l;
            }

            // combine: group1 publishes partials into dead LDS
            if (grp == 1) {
                #pragma unroll
                for (int rt = 0; rt < 2; ++rt) {
                    if (lg == 0) cmbL[wg * 32 + rt * 16 + lr] = lsum[rt];
                    #pragma unroll
                    for (int r2 = 0; r2 < 4; ++r2) {
                        const int row = wg * 32 + rt * 16 + lg * 4 + r2;
                        #pragma unroll
                        for (int nt = 0; nt < 8; ++nt)
                            cmbO[row * 130 + nt * 16 + lr] = oacc[rt][nt][r2];
                    }
                }
            }
            __syncthreads();
            if (grp == 0) {
                #pragma unroll
                for (int rt = 0; rt < 2; ++rt) {
                    const int qrow = q0 + wg * 32 + rt * 16 + lr;
                    float tot = lsum[rt] + cmbL[wg * 32 + rt * 16 + lr];
                    float invq = (qrow < L) ? 1.0f / tot : 0.0f;
                    #pragma unroll
                    for (int r2 = 0; r2 < 4; ++r2) {
                        const float invr = __shfl(invq, lg * 4 + r2);
                        const int row = wg * 32 + rt * 16 + lg * 4 + r2;
                        #pragma unroll
                        for (int nt = 0; nt < 8; ++nt) {
                            const int col = nt * 16 + lr;
                            outb[(size_t)row * D_ + col] =
                                (oacc[rt][nt][r2] + cmbO[row * 130 + col]) * invr;
                        }
                    }
                }
            }
            __syncthreads();   // cmb area becomes K/V staging for next item
        }

        // fetch next item (uniform across block)
        if (tid == 0) slot = 256 + atomicAdd(ctr, 1);
        __syncthreads();
        item = slot;
        __syncthreads();
    }
}

// ---------------------------------------------------------------------------
extern "C" void kernel_launch(void* const* d_in, const int* in_sizes, int n_in,
                              void* d_out, int out_size, void* d_ws, size_t ws_size,
                              hipStream_t stream) {
    const float* x    = (const float*)d_in[0];
    const int*   vlen = (const int*)d_in[1];
    const float* Wq   = (const float*)d_in[2];
    const float* bq   = (const float*)d_in[3];
    const float* Wk   = (const float*)d_in[4];
    const float* bk   = (const float*)d_in[5];
    const float* Wv   = (const float*)d_in[6];
    const float* bv   = (const float*)d_in[7];
    float* out = (float*)d_out;

    // ws layout: [W^T bf16 x3 | q bf16 | k bf16 | v^T bf16 | atomic ctr]
    unsigned short* wt  = (unsigned short*)d_ws;                  // 3*128*128
    unsigned short* qws = (unsigned short*)((char*)d_ws + 98304);
    unsigned short* kws = qws + (size_t)B_ * N_ * D_;
    unsigned short* vtws = kws + (size_t)B_ * N_ * D_;
    int* ctr = (int*)((char*)d_ws + 98304 + 3 * (size_t)B_ * N_ * D_ * 2);

    wtrans_kernel<<<48, 256, 0, stream>>>(Wq, Wk, Wv, wt, ctr);
    proj_kernel<<<(B_ * N_) / 64, 256, 0, stream>>>(x, wt, bq, bk, bv, qws, kws, vtws);
    attn_kernel<<<256, 512, 0, stream>>>(qws, kws, vtws, vlen, out, ctr);
}

// Round 14
// 64.216 us; speedup vs baseline: 1.4777x; 1.0452x over previous
//
#include <hip/hip_runtime.h>
#include <hip/hip_bf16.h>
#include <stdint.h>

#define B_ 64
#define N_ 1024
#define D_ 128

typedef __attribute__((ext_vector_type(8))) short bf16x8;
typedef __attribute__((ext_vector_type(4))) float f32x4;

__device__ __forceinline__ unsigned short f2bf(float f) {
    union { float f; uint32_t u; } v; v.f = f;
    uint32_t u = v.u;
    return (unsigned short)((u + 0x7FFFu + ((u >> 16) & 1u)) >> 16);
}

// ---------------------------------------------------------------------------
// Kernel 1: W (f32 [k=128][d=128]) -> bf16 W^T [d][k]; also zeroes the
// attn work counter (replaces hipMemsetAsync).
__global__ __launch_bounds__(256) void wtrans_kernel(
    const float* __restrict__ Wq, const float* __restrict__ Wk,
    const float* __restrict__ Wv, unsigned short* __restrict__ wt,
    int* __restrict__ ctr)
{
    if (blockIdx.x == 0 && threadIdx.x == 0) ctr[0] = 0;
    int p = blockIdx.x >> 4;
    int seg = blockIdx.x & 15;
    const float* W = (p == 0) ? Wq : (p == 1) ? Wk : Wv;
    unsigned short* dst = wt + p * (D_ * D_);
    for (int i = 0; i < 4; ++i) {
        int idx = seg * 1024 + i * 256 + (int)threadIdx.x;
        int k = idx >> 7, d = idx & 127;
        dst[d * D_ + k] = f2bf(W[idx]);
    }
}

// ---------------------------------------------------------------------------
// Kernel 2: QKV projection. NEW vs r13:
//  (a) blocks whose 64 rows are all >= valid_lens[b] exit immediately --
//      downstream masking makes their (poisoned, finite-tiny) q/k/v harmless,
//      E[L]=N/2 so ~half the proj work and writes vanish;
//  (b) q/k stores staged through LDS (ws is dead post-MFMA) and written as
//      coalesced 16B bf16x8 -- replaces 64 scalar 2B stores per thread.
// q scaled by (1/sqrt(128))*log2(e) for attn's exp2-native softmax.
__global__ __launch_bounds__(256) void proj_kernel(
    const float* __restrict__ x,
    const unsigned short* __restrict__ wtg,
    const float* __restrict__ bq, const float* __restrict__ bk,
    const float* __restrict__ bv,
    const int* __restrict__ valid_lens,
    unsigned short* __restrict__ qo, unsigned short* __restrict__ ko,
    unsigned short* __restrict__ vto)
{
    __shared__ alignas(16) unsigned short xs[64 * 136];
    __shared__ alignas(16) unsigned short ws[128 * 136];
    const int tid = threadIdx.x;
    const int row0 = blockIdx.x * 64;
    const int b = row0 >> 10, n0 = row0 & 1023;

    if (n0 >= valid_lens[b]) return;   // block-uniform: rows never used

    for (int it = 0; it < 8; ++it) {
        int idx4 = it * 256 + tid;
        int r = idx4 >> 5, c4 = (idx4 & 31) * 4;
        const float4 v = *(const float4*)&x[(size_t)(row0 + r) * D_ + c4];
        unsigned short tmp[4] = { f2bf(v.x), f2bf(v.y), f2bf(v.z), f2bf(v.w) };
        *(uint2*)&xs[r * 136 + c4] = *(uint2*)tmp;
    }

    const int wave = tid >> 6, lane = tid & 63;
    const int lr = lane & 15, lg = lane >> 4;
    const f32x4 zero4 = {0.f, 0.f, 0.f, 0.f};

    for (int p = 0; p < 3; ++p) {
        __syncthreads();   // xs ready (p=0) / prior ws uses done (p>0)
        const unsigned short* wsrc = wtg + p * (D_ * D_);
        for (int it = 0; it < 8; ++it) {
            int idx8 = it * 256 + tid;
            int r = idx8 >> 4, c8 = (idx8 & 15) * 8;
            *(bf16x8*)&ws[r * 136 + c8] = *(const bf16x8*)&wsrc[idx8 * 8];
        }
        __syncthreads();

        bf16x8 a[4];
        for (int kk = 0; kk < 4; ++kk)
            a[kk] = *(const bf16x8*)&xs[(wave * 16 + lr) * 136 + kk * 32 + lg * 8];
        f32x4 acc[8];
        for (int nt = 0; nt < 8; ++nt) acc[nt] = zero4;
        for (int kk = 0; kk < 4; ++kk)
            for (int nt = 0; nt < 8; ++nt) {
                bf16x8 bfr = *(const bf16x8*)&ws[(nt * 16 + lr) * 136 + kk * 32 + lg * 8];
                acc[nt] = __builtin_amdgcn_mfma_f32_16x16x32_bf16(a[kk], bfr, acc[nt], 0, 0, 0);
            }

        if (p < 2) {
            const float* bias = (p == 0) ? bq : bk;
            unsigned short* outp = (p == 0) ? qo : ko;
            // q: 1/sqrt(128) * log2(e) folded (exp2-native softmax)
            const float sc = (p == 0) ? 0.12751741388f : 1.0f;
            __syncthreads();   // all waves done reading ws (W^T)
            for (int nt = 0; nt < 8; ++nt) {
                int d = nt * 16 + lr;
                float bb = bias[d];
                for (int r = 0; r < 4; ++r)
                    ws[(wave * 16 + lg * 4 + r) * 136 + d] = f2bf((acc[nt][r] + bb) * sc);
            }
            __syncthreads();
            // coalesced 16B stores: 64 rows x 128 cols
            for (int it = 0; it < 4; ++it) {
                int idx = it * 256 + tid;
                int r = idx >> 4, c8 = (idx & 15) * 8;
                *(bf16x8*)&outp[(size_t)(row0 + r) * D_ + c8] =
                    *(const bf16x8*)&ws[r * 136 + c8];
            }
        } else {
            __syncthreads();   // everyone done reading ws (W^T)
            for (int nt = 0; nt < 8; ++nt) {
                int d = nt * 16 + lr;
                float bb = bv[d];
                for (int r = 0; r < 4; ++r)
                    ws[d * 72 + wave * 16 + lg * 4 + r] = f2bf(acc[nt][r] + bb);
            }
            __syncthreads();
            unsigned short* dst = vto + ((size_t)b * D_) * N_ + n0;
            for (int it = 0; it < 4; ++it) {
                int idx = it * 256 + tid;
                int d = idx >> 3, c8 = (idx & 7) * 8;
                *(bf16x8*)&dst[(size_t)d * N_ + c8] = *(const bf16x8*)&ws[d * 72 + c8];
            }
        }
    }
}

// ---------------------------------------------------------------------------
// Kernel 3: persistent flash attention — IDENTICAL to round 13 (passing,
// attn ~37.5us). exp2-native softmax, hoisted masks, cvt_pk packing,
// butterfly P-exchange, K/V double-buffer, 1 barrier/round, dynamic items.
__global__ __launch_bounds__(512, 1) void attn_kernel(
    const unsigned short* __restrict__ qg, const unsigned short* __restrict__ kg,
    const unsigned short* __restrict__ vtg, const int* __restrict__ valid_lens,
    float* __restrict__ out, int* __restrict__ ctr)
{
    // smem (ushorts): ks[grp][buf][64*136] | vt[grp][buf][128*72]
    __shared__ alignas(16) unsigned short smem[71680];
    __shared__ int slot;

    const int tid = threadIdx.x;
    const int wave = tid >> 6, lane = tid & 63;
    const int lr = lane & 15, lg = lane >> 4;
    const int grp = tid >> 8;            // 0: waves 0-3, 1: waves 4-7
    const int wg = wave & 3;             // q-row group within the item
    const int t256 = tid & 255;
    const int k_r = t256 >> 4, k_c = (t256 & 15) * 8;
    const int v_d = t256 >> 3, v_c = (t256 & 7) * 8;
    unsigned short* const ks_base = smem + grp * 17408;          // 2 bufs of 8704
    unsigned short* const vt_base = smem + 34816 + grp * 18432;  // 2 bufs of 9216
    float* const cmbO = (float*)smem;                 // [128][130] (dead alias)
    float* const cmbL = ((float*)smem) + 16640;       // [128]
    const f32x4 zero4 = {0.f, 0.f, 0.f, 0.f};
    const bool hbit = (lg >> 1) != 0;
    const bool mbit = (lg & 1) != 0;

    int item = blockIdx.x;
    while (item < 512) {
        const int qt = 7 - (item >> 6);           // heavy (high-qt) items first
        const int b  = item & 63;
        const int L  = valid_lens[b];
        const int q0 = qt * 128;
        float* outb = out + ((size_t)b * N_ + q0) * D_;

        if (q0 >= L) {
            #pragma unroll
            for (int it = 0; it < 8; ++it) {
                int idx4 = it * 512 + tid;
                int r = idx4 >> 5, c4 = (idx4 & 31) * 4;
                float4 z; z.x = z.y = z.z = z.w = 0.f;
                *(float4*)&outb[(size_t)r * D_ + c4] = z;
            }
        } else {
            const int ntiles = (L + 63) >> 6;
            const int H = (ntiles + 1) >> 1;
            const int myStart = grp ? H : 0;
            const int myCnt = grp ? (ntiles - H) : H;
            const unsigned short* kgb = kg + (size_t)b * N_ * D_;
            const unsigned short* vtb = vtg + (size_t)b * D_ * N_;

            // Q fragments (B-operand in swapped QK^T: lane lr = q-row)
            bf16x8 aq[2][4];
            #pragma unroll
            for (int rt = 0; rt < 2; ++rt) {
                const unsigned short* qrow =
                    qg + ((size_t)b * N_ + q0 + wg * 32 + rt * 16 + lr) * D_;
                #pragma unroll
                for (int kk = 0; kk < 4; ++kk)
                    aq[rt][kk] = *(const bf16x8*)&qrow[kk * 32 + lg * 8];
            }

            f32x4 oacc[2][8];
            #pragma unroll
            for (int rt = 0; rt < 2; ++rt)
                #pragma unroll
                for (int i = 0; i < 8; ++i) oacc[rt][i] = zero4;
            float lsum[2] = {0.f, 0.f};

            bf16x8 kreg[4], vreg[4];

            // prologue: stage my stream's first tile into buf0
            if (myCnt > 0) {
                const int kv0 = myStart * 64;
                #pragma unroll
                for (int it = 0; it < 4; ++it)
                    kreg[it] = *(const bf16x8*)&kgb[(size_t)(kv0 + it * 16 + k_r) * D_ + k_c];
                #pragma unroll
                for (int it = 0; it < 4; ++it)
                    vreg[it] = *(const bf16x8*)&vtb[(size_t)(it * 32 + v_d) * N_ + kv0 + v_c];
                #pragma unroll
                for (int it = 0; it < 4; ++it)
                    *(bf16x8*)&ks_base[(it * 16 + k_r) * 136 + k_c] = kreg[it];
                #pragma unroll
                for (int it = 0; it < 4; ++it)
                    *(bf16x8*)&vt_base[(it * 32 + v_d) * 72 + v_c] = vreg[it];
            }
            __syncthreads();

            for (int r = 0; r < H; ++r) {
                const bool valid = (r < myCnt);
                const int kv0 = (myStart + r) * 64;
                const int ko_cur = (r & 1) ? 8704 : 0;     // branch-free buf select
                const int vo_cur = (r & 1) ? 9216 : 0;
                unsigned short* const ks_my = ks_base + ko_cur;
                unsigned short* const vt_my = vt_base + vo_cur;

                if (r + 1 < myCnt) {   // issue next-tile loads before compute
                    const int kvn = kv0 + 64;
                    #pragma unroll
                    for (int it = 0; it < 4; ++it)
                        kreg[it] = *(const bf16x8*)&kgb[(size_t)(kvn + it * 16 + k_r) * D_ + k_c];
                    #pragma unroll
                    for (int it = 0; it < 4; ++it)
                        vreg[it] = *(const bf16x8*)&vtb[(size_t)(it * 32 + v_d) * N_ + kvn + v_c];
                    __builtin_amdgcn_sched_barrier(0);
                }

                if (valid) {
                    // S^T = K Q^T (A=K-frag, B=Q-frag). col=lr=q-row, row=kv.
                    f32x4 s[2][4];
                    __builtin_amdgcn_s_setprio(1);
                    #pragma unroll
                    for (int nt = 0; nt < 4; ++nt) {
                        s[0][nt] = zero4; s[1][nt] = zero4;
                        #pragma unroll
                        for (int kk = 0; kk < 4; ++kk) {
                            bf16x8 bk_ = *(const bf16x8*)&ks_my[(nt * 16 + lr) * 136 + kk * 32 + lg * 8];
                            s[0][nt] = __builtin_amdgcn_mfma_f32_16x16x32_bf16(bk_, aq[0][kk], s[0][nt], 0, 0, 0);
                            s[1][nt] = __builtin_amdgcn_mfma_f32_16x16x32_bf16(bk_, aq[1][kk], s[1][nt], 0, 0, 0);
                        }
                    }
                    __builtin_amdgcn_s_setprio(0);

                    // p = exp2(s); full tiles (group-uniform) skip mask ops.
                    uint32_t pwv[2][8];
                    if (kv0 + 64 <= L) {
                        #pragma unroll
                        for (int nt = 0; nt < 4; ++nt)
                            #pragma unroll
                            for (int rt = 0; rt < 2; ++rt) {
                                float e0 = __builtin_amdgcn_exp2f(s[rt][nt][0]);
                                float e1 = __builtin_amdgcn_exp2f(s[rt][nt][1]);
                                float e2 = __builtin_amdgcn_exp2f(s[rt][nt][2]);
                                float e3 = __builtin_amdgcn_exp2f(s[rt][nt][3]);
                                lsum[rt] += (e0 + e1) + (e2 + e3);
                                uint32_t w0, w1;
                                asm("v_cvt_pk_bf16_f32 %0, %1, %2" : "=v"(w0) : "v"(e0), "v"(e1));
                                asm("v_cvt_pk_bf16_f32 %0, %1, %2" : "=v"(w1) : "v"(e2), "v"(e3));
                                pwv[rt][nt * 2 + 0] = w0;
                                pwv[rt][nt * 2 + 1] = w1;
                            }
                    } else {
                        #pragma unroll
                        for (int nt = 0; nt < 4; ++nt) {
                            const int kvb = kv0 + nt * 16 + lg * 4;
                            #pragma unroll
                            for (int rt = 0; rt < 2; ++rt) {
                                float e0 = (kvb + 0 < L) ? __builtin_amdgcn_exp2f(s[rt][nt][0]) : 0.f;
                                float e1 = (kvb + 1 < L) ? __builtin_amdgcn_exp2f(s[rt][nt][1]) : 0.f;
                                float e2 = (kvb + 2 < L) ? __builtin_amdgcn_exp2f(s[rt][nt][2]) : 0.f;
                                float e3 = (kvb + 3 < L) ? __builtin_amdgcn_exp2f(s[rt][nt][3]) : 0.f;
                                lsum[rt] += (e0 + e1) + (e2 + e3);
                                uint32_t w0, w1;
                                asm("v_cvt_pk_bf16_f32 %0, %1, %2" : "=v"(w0) : "v"(e0), "v"(e1));
                                asm("v_cvt_pk_bf16_f32 %0, %1, %2" : "=v"(w1) : "v"(e2), "v"(e3));
                                pwv[rt][nt * 2 + 0] = w0;
                                pwv[rt][nt * 2 + 1] = w1;
                            }
                        }
                    }

                    // butterfly P-exchange among lanes {lr+16*lg} -> A-frags
                    #pragma unroll
                    for (int rt = 0; rt < 2; ++rt) {
                        uint32_t sh[4], so[4];
                        #pragma unroll
                        for (int i = 0; i < 4; ++i) {
                            int i0 = (i >> 1) * 4 + (i & 1);  // set0 word
                            sh[i] = hbit ? pwv[rt][i0 + 2] : pwv[rt][i0];
                            so[i] = hbit ? pwv[rt][i0] : pwv[rt][i0 + 2];
                        }
                        uint32_t rv[4];
                        #pragma unroll
                        for (int i = 0; i < 4; ++i)
                            rv[i] = __shfl_xor((int)so[i], 32);
                        const bool c2 = (hbit != mbit);
                        uint32_t s2[4], kp[4];
                        #pragma unroll
                        for (int i = 0; i < 4; ++i) {
                            s2[i] = c2 ? sh[i] : rv[i];
                            kp[i] = c2 ? rv[i] : sh[i];
                        }
                        uint32_t r2v[4];
                        #pragma unroll
                        for (int i = 0; i < 4; ++i)
                            r2v[i] = __shfl_xor((int)s2[i], 16);
                        uint32_t apw[2][4];
                        #pragma unroll
                        for (int kk = 0; kk < 2; ++kk)
                            #pragma unroll
                            for (int c = 0; c < 2; ++c) {
                                uint32_t kw = kp[kk * 2 + c], rw = r2v[kk * 2 + c];
                                apw[kk][c]     = mbit ? rw : kw;
                                apw[kk][2 + c] = mbit ? kw : rw;
                            }
                        // O += P V (V from LDS)
                        __builtin_amdgcn_s_setprio(1);
                        #pragma unroll
                        for (int kk = 0; kk < 2; ++kk) {
                            bf16x8 ap = *(bf16x8*)&apw[kk][0];
                            #pragma unroll
                            for (int nt = 0; nt < 8; ++nt) {
                                bf16x8 bv_ = *(const bf16x8*)&vt_my[(nt * 16 + lr) * 72 + kk * 32 + lg * 8];
                                oacc[rt][nt] = __builtin_amdgcn_mfma_f32_16x16x32_bf16(ap, bv_, oacc[rt][nt], 0, 0, 0);
                            }
                        }
                        __builtin_amdgcn_s_setprio(0);
                    }
                }

                // write next tile into the idle buffer (its readers finished
                // last round, sealed by that round's barrier)
                if (r + 1 < myCnt) {
                    unsigned short* const ks_nx = ks_base + (ko_cur ^ 8704);
                    unsigned short* const vt_nx = vt_base + (vo_cur ^ 9216);
                    #pragma unroll
                    for (int it = 0; it < 4; ++it)
                        *(bf16x8*)&ks_nx[(it * 16 + k_r) * 136 + k_c] = kreg[it];
                    #pragma unroll
                    for (int it = 0; it < 4; ++it)
                        *(bf16x8*)&vt_nx[(it * 32 + v_d) * 72 + v_c] = vreg[it];
                }
                __syncthreads();
            }

            // reduce lane-local denominators across the 4 lg-copies of each q-row
            #pragma unroll
            for (int rt = 0; rt < 2; ++rt) {
                float l = lsum[rt];
                l += __shfl_xor(l, 16);
                l += __shfl_xor(l, 32);
                lsum[rt] = l;
            }

            // combine: group1 publishes partials into dead LDS
            if (grp == 1) {
                #pragma unroll
                for (int rt = 0; rt < 2; ++rt) {
                    if (lg == 0) cmbL[wg * 32 + rt * 16 + lr] = lsum[rt];
                    #pragma unroll
                    for (int r2 = 0; r2 < 4; ++r2) {
                        const int row = wg * 32 + rt * 16 + lg * 4 + r2;
                        #pragma unroll
                        for (int nt = 0; nt < 8; ++nt)
                            cmbO[row * 130 + nt * 16 + lr] = oacc[rt][nt][r2];
                    }
                }
            }
            __syncthreads();
            if (grp == 0) {
                #pragma unroll
                for (int rt = 0; rt < 2; ++rt) {
                    const int qrow = q0 + wg * 32 + rt * 16 + lr;
                    float tot = lsum[rt] + cmbL[wg * 32 + rt * 16 + lr];
                    float invq = (qrow < L) ? 1.0f / tot : 0.0f;
                    #pragma unroll
                    for (int r2 = 0; r2 < 4; ++r2) {
                        const float invr = __shfl(invq, lg * 4 + r2);
                        const int row = wg * 32 + rt * 16 + lg * 4 + r2;
                        #pragma unroll
                        for (int nt = 0; nt < 8; ++nt) {
                            const int col = nt * 16 + lr;
                            outb[(size_t)row * D_ + col] =
                                (oacc[rt][nt][r2] + cmbO[row * 130 + col]) * invr;
                        }
                    }
                }
            }
            __syncthreads();   // cmb area becomes K/V staging for next item
        }

        // fetch next item (uniform across block)
        if (tid == 0) slot = 256 + atomicAdd(ctr, 1);
        __syncthreads();
        item = slot;
        __syncthreads();
    }
}

// ---------------------------------------------------------------------------
extern "C" void kernel_launch(void* const* d_in, const int* in_sizes, int n_in,
                              void* d_out, int out_size, void* d_ws, size_t ws_size,
                              hipStream_t stream) {
    const float* x    = (const float*)d_in[0];
    const int*   vlen = (const int*)d_in[1];
    const float* Wq   = (const float*)d_in[2];
    const float* bq   = (const float*)d_in[3];
    const float* Wk   = (const float*)d_in[4];
    const float* bk   = (const float*)d_in[5];
    const float* Wv   = (const float*)d_in[6];
    const float* bv   = (const float*)d_in[7];
    float* out = (float*)d_out;

    // ws layout: [W^T bf16 x3 | q bf16 | k bf16 | v^T bf16 | atomic ctr]
    unsigned short* wt  = (unsigned short*)d_ws;                  // 3*128*128
    unsigned short* qws = (unsigned short*)((char*)d_ws + 98304);
    unsigned short* kws = qws + (size_t)B_ * N_ * D_;
    unsigned short* vtws = kws + (size_t)B_ * N_ * D_;
    int* ctr = (int*)((char*)d_ws + 98304 + 3 * (size_t)B_ * N_ * D_ * 2);

    wtrans_kernel<<<48, 256, 0, stream>>>(Wq, Wk, Wv, wt, ctr);
    proj_kernel<<<(B_ * N_) / 64, 256, 0, stream>>>(x, wt, bq, bk, bv, vlen, qws, kws, vtws);
    attn_kernel<<<256, 512, 0, stream>>>(qws, kws, vtws, vlen, out, ctr);
}